// Round 1
// baseline (1079.718 us; speedup 1.0000x reference)
//
#include <hip/hip_runtime.h>

typedef __attribute__((ext_vector_type(8))) short short8;
typedef __attribute__((ext_vector_type(4))) float floatx4;

// ---------- helpers ----------
__device__ __forceinline__ unsigned short f2bf(float f) {
  union { float f; unsigned u; } x; x.f = f;
  unsigned u = x.u + 0x7fffu + ((x.u >> 16) & 1u);   // RNE
  return (unsigned short)(u >> 16);
}
__device__ __forceinline__ float bflo(unsigned u) {
  u <<= 16; float f; __builtin_memcpy(&f, &u, 4); return f;
}
__device__ __forceinline__ float bfhi(unsigned u) {
  u &= 0xffff0000u; float f; __builtin_memcpy(&f, &u, 4); return f;
}

// ---------- constants ----------
// B=8, H=W=128, DIM=512, NH=8, HD=64, K=7, R=3
// M = 8*128*128 = 131072 rows; GEMM: [M,512] x [512,1024] -> [M,1024]

// ---------- kernel 1: convert x fp32 -> bf16 ----------
__global__ __launch_bounds__(256) void cvt_x(const float4* __restrict__ x,
                                             uint2* __restrict__ o) {
  size_t idx = (size_t)blockIdx.x * 256 + threadIdx.x;   // 16,777,216 float4s
  float4 v = x[idx];
  uint2 r;
  r.x = (unsigned)f2bf(v.x) | ((unsigned)f2bf(v.y) << 16);
  r.y = (unsigned)f2bf(v.z) | ((unsigned)f2bf(v.w) << 16);
  o[idx] = r;
}

// ---------- kernel 2: convert + transpose W (fold q scale) ----------
// W [512][1024] fp32 -> Wt [1024][512] bf16, cols 0..511 (q half) scaled by 0.125
__global__ __launch_bounds__(256) void cvt_w(const float* __restrict__ w,
                                             unsigned short* __restrict__ wt) {
  int tid = blockIdx.x * 256 + threadIdx.x;   // 0..524287
  int n = tid >> 9, k = tid & 511;
  float v = w[k * 1024 + n];
  if (n < 512) v *= 0.125f;                   // HEAD_DIM^-0.5
  wt[tid] = f2bf(v);
}

// ---------- kernel 3: bf16 MFMA GEMM (A row-major, B pre-transposed N x K) ----------
// C[m][n] = sum_k A[m][k] * Bt[n][k];  BM=BN=128, BK=32; 256 thr = 4 waves, 64x64/wave
__global__ __launch_bounds__(256) void gemm_bt(const unsigned short* __restrict__ A,
                                               const unsigned short* __restrict__ Bt,
                                               unsigned short* __restrict__ C) {
  __shared__ unsigned short lds_a[4 * 128 * 8];   // [kgrp][m][8]  8 KB
  __shared__ unsigned short lds_b[4 * 128 * 8];   // [kgrp][n][8]  8 KB

  const int t = threadIdx.x;
  const int mtile = blockIdx.x >> 3;   // 1024 m-tiles
  const int ntile = blockIdx.x & 7;    // 8 n-tiles (consecutive blocks share A tile -> L2)
  const int m0 = mtile * 128, n0 = ntile * 128;
  const int wave = t >> 6, lane = t & 63;
  const int wm = (wave & 1) * 64, wn = (wave >> 1) * 64;
  const int kg = lane >> 4, rr = lane & 15;

  floatx4 acc[4][4] = {};

  for (int k0 = 0; k0 < 512; k0 += 32) {
    __syncthreads();
#pragma unroll
    for (int s = 0; s < 2; ++s) {
      int S = t + s * 256;                 // 0..511
      int kgrp = S >> 7, row = S & 127;
      const uint4 va = *(const uint4*)&A[(size_t)(m0 + row) * 512 + k0 + kgrp * 8];
      *(uint4*)&lds_a[S * 8] = va;
      const uint4 vb = *(const uint4*)&Bt[(size_t)(n0 + row) * 512 + k0 + kgrp * 8];
      *(uint4*)&lds_b[S * 8] = vb;
    }
    __syncthreads();

    short8 af[4], bf[4];
#pragma unroll
    for (int i = 0; i < 4; ++i) {
      af[i] = *(const short8*)&lds_a[(kg * 128 + wm + i * 16 + rr) * 8];
      bf[i] = *(const short8*)&lds_b[(kg * 128 + wn + i * 16 + rr) * 8];
    }
#pragma unroll
    for (int i = 0; i < 4; ++i)
#pragma unroll
      for (int j = 0; j < 4; ++j)
        acc[i][j] = __builtin_amdgcn_mfma_f32_16x16x32_bf16(af[i], bf[j], acc[i][j], 0, 0, 0);
  }

  // C/D layout (verified m89): col = lane&15, row = (lane>>4)*4 + reg
#pragma unroll
  for (int i = 0; i < 4; ++i) {
    int mrow = m0 + wm + i * 16 + (lane >> 4) * 4;
#pragma unroll
    for (int j = 0; j < 4; ++j) {
      int ncol = n0 + wn + j * 16 + (lane & 15);
#pragma unroll
      for (int r = 0; r < 4; ++r)
        C[(size_t)(mrow + r) * 1024 + ncol] = f2bf(acc[i][j][r]);
    }
  }
}

// ---------- kernel 4: neighborhood attention logits ----------
// grid: (b, h, 8x8 tiles of 16x16 pixels) = 4096 blocks x 256 threads
// out[b][h][i][j][ki*7+kj] = dot64(q[b,i,j,h,:], k[b, clip(i-3)+ki, clip(j-3)+kj, h, :])
__global__ __launch_bounds__(256) void attn_kernel(const unsigned short* __restrict__ QK,
                                                   float* __restrict__ out) {
  // LDS: 22x22 neighborhood x 64 dims bf16, chunk-rotation swizzle on 8-elem groups
  __shared__ unsigned short lds_k[22 * 22 * 64];   // 61,952 B

  const int blk = blockIdx.x;
  const int tile = blk & 63;
  const int h = (blk >> 6) & 7;
  const int b = blk >> 9;
  const int i0 = (tile >> 3) * 16, j0 = (tile & 7) * 16;
  const int row_lo = min(max(i0 - 3, 0), 121);
  const int col_lo = min(max(j0 - 3, 0), 121);

  // stage k neighborhood: 22*22*8 uint4 chunks
  for (int s = threadIdx.x; s < 22 * 22 * 8; s += 256) {
    int dgrp = s & 7;
    int rc = s >> 3;
    int r = rc / 22, c = rc - r * 22;
    int rg = min(row_lo + r, 127), cg = min(col_lo + c, 127);
    size_t gidx = ((size_t)((b * 128 + rg) * 128 + cg)) * 1024 + 512 + h * 64 + dgrp * 8;
    uint4 v = *(const uint4*)&QK[gidx];
    int phys = (dgrp + c) & 7;                       // swizzle breaks 128B-stride conflicts
    *(uint4*)&lds_k[(r * 22 + c) * 64 + phys * 8] = v;
  }

  // load q into registers as 64 floats
  const int li = threadIdx.x >> 4, lj = threadIdx.x & 15;
  const int i = i0 + li, j = j0 + lj;
  float qf[64];
  {
    size_t qidx = ((size_t)((b * 128 + i) * 128 + j)) * 1024 + h * 64;
#pragma unroll
    for (int g = 0; g < 8; ++g) {
      uint4 v = *(const uint4*)&QK[qidx + g * 8];
      qf[g * 8 + 0] = bflo(v.x); qf[g * 8 + 1] = bfhi(v.x);
      qf[g * 8 + 2] = bflo(v.y); qf[g * 8 + 3] = bfhi(v.y);
      qf[g * 8 + 4] = bflo(v.z); qf[g * 8 + 5] = bfhi(v.z);
      qf[g * 8 + 6] = bflo(v.w); qf[g * 8 + 7] = bfhi(v.w);
    }
  }
  __syncthreads();

  const int base_r = min(max(i - 3, 0), 121) - row_lo;
  const int base_c = min(max(j - 3, 0), 121) - col_lo;
  float* outp = out + ((size_t)((b * 8 + h) * 16384 + i * 128 + j)) * 49;

#pragma unroll 1
  for (int ki = 0; ki < 7; ++ki) {
#pragma unroll 1
    for (int kj = 0; kj < 7; ++kj) {
      const int rel_c = base_c + kj;
      const unsigned short* kp = &lds_k[((base_r + ki) * 22 + rel_c) * 64];
      float acc = 0.f;
#pragma unroll
      for (int g = 0; g < 8; ++g) {
        int phys = (g + rel_c) & 7;
        uint4 v = *(const uint4*)&kp[phys * 8];
        acc += qf[g * 8 + 0] * bflo(v.x) + qf[g * 8 + 1] * bfhi(v.x)
             + qf[g * 8 + 2] * bflo(v.y) + qf[g * 8 + 3] * bfhi(v.y)
             + qf[g * 8 + 4] * bflo(v.z) + qf[g * 8 + 5] * bfhi(v.z)
             + qf[g * 8 + 6] * bflo(v.w) + qf[g * 8 + 7] * bfhi(v.w);
      }
      outp[ki * 7 + kj] = acc;
    }
  }
}

// ---------- launch ----------
extern "C" void kernel_launch(void* const* d_in, const int* in_sizes, int n_in,
                              void* d_out, int out_size, void* d_ws, size_t ws_size,
                              hipStream_t stream) {
  const float* x = (const float*)d_in[0];     // [8,128,128,512] fp32
  const float* w = (const float*)d_in[1];     // [512,1024] fp32
  float* out = (float*)d_out;                 // [8,8,128,128,49] fp32

  // workspace layout (bf16 shorts): x_bf16 | Wt_bf16 | qk_bf16  = 403.7 MB total
  unsigned short* xb = (unsigned short*)d_ws;        // 67,108,864
  unsigned short* wt = xb + 67108864;                // 524,288
  unsigned short* qk = wt + 524288;                  // 134,217,728

  cvt_x<<<65536, 256, 0, stream>>>((const float4*)x, (uint2*)xb);
  cvt_w<<<2048, 256, 0, stream>>>(w, wt);
  gemm_bt<<<8192, 256, 0, stream>>>(xb, wt, qk);
  attn_kernel<<<4096, 256, 0, stream>>>(qk, out);
}